// Round 6
// baseline (2459.952 us; speedup 1.0000x reference)
//
#include <hip/hip_runtime.h>

#define T_STEPS 512
#define H_DIM   2048
#define G_DIM   8192   // 4*H
#define NGUESS  4096
#define NWG     256

typedef unsigned long long u64;

// exp2-based fast activations (v_exp_f32 + v_rcp_f32), saturation-safe.
#define LOG2E 1.4426950408889634f
__device__ __forceinline__ float fast_sig(float x) {
    return __builtin_amdgcn_rcpf(1.0f + __builtin_amdgcn_exp2f(-LOG2E * x));
}
__device__ __forceinline__ float fast_tanh(float x) {
    float t = __builtin_amdgcn_exp2f(2.0f * LOG2E * x);
    return 1.0f - 2.0f * __builtin_amdgcn_rcpf(t + 1.0f);
}

#define ALOAD(p)    __hip_atomic_load((p), __ATOMIC_RELAXED, __HIP_MEMORY_SCOPE_AGENT)
#define ASTORE(p,v) __hip_atomic_store((p), (v), __ATOMIC_RELAXED, __HIP_MEMORY_SCOPE_AGENT)

// ---------------------------------------------------------------------------
// Kernel 1: gather embeddings -> xs[T][2048]
// ---------------------------------------------------------------------------
__global__ void embed_kernel(const int* __restrict__ guesses,
                             const int* __restrict__ feedbacks,
                             const float* __restrict__ gemb,
                             const float* __restrict__ femb,
                             float* __restrict__ xs) {
    int t = blockIdx.x;                      // 512 blocks
    int g = guesses[t];
    int f = feedbacks[t];
    const float4* gs = (const float4*)(gemb + (size_t)g * 1024);
    const float4* fs = (const float4*)(femb + (size_t)f * 1024);
    float4* xg = (float4*)(xs + (size_t)t * H_DIM);
    int tid = threadIdx.x;                   // 256 threads
    xg[tid]       = gs[tid];
    xg[256 + tid] = fs[tid];
}

// ---------------------------------------------------------------------------
// Kernel 2: GX[t][r] = dot(W_ih[r], xs[t]) + b_ih[r] + b_hh[r]
// ---------------------------------------------------------------------------
__global__ void gx_gemm(const float* __restrict__ xs,
                        const float* __restrict__ Wih,
                        const float* __restrict__ bih,
                        const float* __restrict__ bhh,
                        float* __restrict__ GX) {
    __shared__ float As[64][17];
    __shared__ float Bs[64][17];
    int r0 = blockIdx.x * 64;
    int t0 = blockIdx.y * 64;
    int tid = threadIdx.x;
    int tx = tid & 15;
    int ty = tid >> 4;
    int lr = tid >> 2;
    int lk = (tid & 3) * 4;
    float acc[4][4] = {};

    for (int k0 = 0; k0 < H_DIM; k0 += 16) {
        const float* xp = xs  + (size_t)(t0 + lr) * H_DIM + k0 + lk;
        const float* wp = Wih + (size_t)(r0 + lr) * H_DIM + k0 + lk;
        As[lr][lk + 0] = xp[0]; As[lr][lk + 1] = xp[1];
        As[lr][lk + 2] = xp[2]; As[lr][lk + 3] = xp[3];
        Bs[lr][lk + 0] = wp[0]; Bs[lr][lk + 1] = wp[1];
        Bs[lr][lk + 2] = wp[2]; Bs[lr][lk + 3] = wp[3];
        __syncthreads();
#pragma unroll
        for (int kk = 0; kk < 16; ++kk) {
            float a[4], b[4];
#pragma unroll
            for (int i = 0; i < 4; ++i) a[i] = As[ty * 4 + i][kk];
#pragma unroll
            for (int j = 0; j < 4; ++j) b[j] = Bs[tx * 4 + j][kk];
#pragma unroll
            for (int i = 0; i < 4; ++i)
#pragma unroll
                for (int j = 0; j < 4; ++j) acc[i][j] += a[i] * b[j];
        }
        __syncthreads();
    }
#pragma unroll
    for (int i = 0; i < 4; ++i)
#pragma unroll
        for (int j = 0; j < 4; ++j) {
            int t = t0 + ty * 4 + i;
            int r = r0 + tx * 4 + j;
            GX[(size_t)t * G_DIM + r] = acc[i][j] + bih[r] + bhh[r];
        }
}

// ---------------------------------------------------------------------------
// Kernel 3: sequential LSTM, W_hh register-resident, barrier-free,
// TWO-PHASE readiness to kill poll congestion:
//   Phase A: wave 0 polls 256 per-producer flags (1 KB, coalesced) until
//            all >= t  (flags are monotonic hints, relaxed stores).
//   Phase B: after syncthreads, ALL threads load their 2 seq-tagged data
//            words ONCE and verify tags (ground truth; rare retry loop).
// Data words: (step<<32)|float_bits, double-buffered by step parity.
// flags/hseq memset to 0 each call -> no ABA across graph replays.
// ---------------------------------------------------------------------------
__global__ void __launch_bounds__(1024, 4)
lstm_loop(const float* __restrict__ Whh,
          const float* __restrict__ GX,
          const float* __restrict__ xs,
          u64* __restrict__ hseq,       // [2][H_DIM] packed (seq, value)
          unsigned* __restrict__ flags, // [NWG] last step produced
          float* __restrict__ hfinal) { // [H_DIM] final h
    __shared__ float h_lds[H_DIM];
    __shared__ float gates[32];

    const int wg   = blockIdx.x;        // 256
    const int base = wg * 8;            // unit base
    const int tid  = threadIdx.x;
    const int lane = tid & 63;
    const int wv   = tid >> 6;          // wave 0..15

    const int r0 = 2 * wv;              // gate rows (gate = r>>3, unit = r&7)
    const int r1 = 2 * wv + 1;
    const int grow0 = (r0 >> 3) * H_DIM + base + (r0 & 7);
    const int grow1 = (r1 >> 3) * H_DIM + base + (r1 & 7);

    // ---- preload W_hh rows into registers/AGPRs (elem j*64+lane) ----
    float w0[32], w1[32];
    {
        const float* W0 = Whh + (size_t)grow0 * H_DIM + lane;
        const float* W1 = Whh + (size_t)grow1 * H_DIM + lane;
#pragma unroll
        for (int j = 0; j < 32; ++j) {
            w0[j] = W0[j * 64];
            w1[j] = W1[j * 64];
        }
    }

    // ---- peeled step t=0: h==0, gates = GX[0] ----
    if (tid < 32)
        gates[tid] = GX[(tid >> 3) * H_DIM + base + (tid & 7)];
    __syncthreads();
    if (tid < 8) {
        int u = tid;
        float gi = gates[0 * 8 + u];
        float gg = gates[2 * 8 + u];
        float go = gates[3 * 8 + u];
        float c  = fast_sig(gi) * fast_tanh(gg);       // c_in = 0 at t=0
        float hn = fast_sig(go) * fast_tanh(c);
        u64 word = (1ull << 32) | (u64)__float_as_uint(hn);
        ASTORE(hseq + H_DIM + base + u, word);
    }
    if (tid == 0) ASTORE(flags + wg, 1u);   // hint: step-1 h produced

    for (int t = 1; t < T_STEPS; ++t) {
        const float* gx = GX + (size_t)t * G_DIM;
        // independent loads issued early (hide under the poll)
        float gxv0 = gx[grow0];
        float gxv1 = gx[grow1];
        float c_in = 0.0f;
        if (tid < 8) c_in = xs[(size_t)t * H_DIM + base + tid];

        const unsigned want = (unsigned)t;

        // ---- Phase A: wave 0 polls the 256 flags (coalesced, 1 KB) ----
        if (wv == 0) {
            const unsigned* fl = flags;
            for (;;) {
                unsigned f0 = ALOAD(fl + lane);
                unsigned f1 = ALOAD(fl + lane + 64);
                unsigned f2 = ALOAD(fl + lane + 128);
                unsigned f3 = ALOAD(fl + lane + 192);
                if ((f0 >= want) & (f1 >= want) & (f2 >= want) & (f3 >= want))
                    break;
                __builtin_amdgcn_s_sleep(1);
            }
        }
        __syncthreads();   // Bf: all producers have (almost surely) published

        // ---- Phase B: single tagged-data pass + verify (rare retry) ----
        u64* slot = hseq + (size_t)(t & 1) * H_DIM;
        u64 wa = ALOAD(slot + tid);
        u64 wb = ALOAD(slot + tid + 1024);
        while (((unsigned)(wa >> 32) != want) | ((unsigned)(wb >> 32) != want)) {
            __builtin_amdgcn_s_sleep(1);
            wa = ALOAD(slot + tid);
            wb = ALOAD(slot + tid + 1024);
        }
        h_lds[tid]        = __uint_as_float((unsigned)wa);
        h_lds[tid + 1024] = __uint_as_float((unsigned)wb);
        __syncthreads();   // B1

        // ---- dot: 2 rows per wave ----
        float acc0 = 0.0f, acc1 = 0.0f;
#pragma unroll
        for (int j = 0; j < 32; ++j) {
            float hv = h_lds[j * 64 + lane];   // 2 lanes/bank: free
            acc0 += w0[j] * hv;
            acc1 += w1[j] * hv;
        }
#pragma unroll
        for (int off = 32; off > 0; off >>= 1) {
            acc0 += __shfl_xor(acc0, off, 64);
            acc1 += __shfl_xor(acc1, off, 64);
        }
        if (lane == 0) {
            gates[r0] = acc0 + gxv0;
            gates[r1] = acc1 + gxv1;
        }
        __syncthreads();   // B2

        if (tid < 8) {
            int u = tid;
            float gi = gates[0 * 8 + u];
            float gf = gates[1 * 8 + u];
            float gg = gates[2 * 8 + u];
            float go = gates[3 * 8 + u];
            float c  = fast_sig(gf) * c_in + fast_sig(gi) * fast_tanh(gg);
            float hn = fast_sig(go) * fast_tanh(c);
            u64 word = ((u64)(unsigned)(t + 1) << 32) | (u64)__float_as_uint(hn);
            ASTORE(hseq + (size_t)((t + 1) & 1) * H_DIM + base + u, word);
            if (t == T_STEPS - 1)
                hfinal[base + u] = hn;   // kernel-end release publishes this
        }
        if (tid == 0) ASTORE(flags + wg, (unsigned)(t + 1));
        // no trailing barrier: flags/tags self-synchronize step t+1; a WG
        // sets flags[wg]=t+1 only after staging step-t data into LDS (B1),
        // so the parity-t slot is dead for it -> 2-slot overwrite safety.
    }
}

// ---------------------------------------------------------------------------
// Kernel 4: logits[r] = dot(W_fc[r], h) + b_fc[r]
// ---------------------------------------------------------------------------
__global__ void fc_kernel(const float* __restrict__ Wfc,
                          const float* __restrict__ bfc,
                          const float* __restrict__ h,
                          float* __restrict__ logits) {
    int wg = blockIdx.x;           // 256
    int tid = threadIdx.x;
    int lane = tid & 63, wv = tid >> 6;
    int r0 = wg * 16;
    const float4* hv = (const float4*)h;
    for (int rr = wv; rr < 16; rr += 4) {
        int r = r0 + rr;
        const float4* wrow = (const float4*)(Wfc + (size_t)r * H_DIM);
        float acc = 0.0f;
#pragma unroll
        for (int c = 0; c < 8; ++c) {
            float4 w4 = wrow[c * 64 + lane];
            float4 h4 = hv[c * 64 + lane];
            acc += w4.x * h4.x + w4.y * h4.y + w4.z * h4.z + w4.w * h4.w;
        }
#pragma unroll
        for (int off = 32; off > 0; off >>= 1) acc += __shfl_xor(acc, off, 64);
        if (lane == 0) logits[r] = acc + bfc[r];
    }
}

// ---------------------------------------------------------------------------
// Kernel 5: softmax over 4096 logits -> out
// ---------------------------------------------------------------------------
__global__ void softmax_kernel(const float* __restrict__ logits,
                               float* __restrict__ out) {
    __shared__ float sm[8];
    int tid = threadIdx.x, lane = tid & 63, wv = tid >> 6;
    float m = -1e30f;
    for (int i = tid; i < NGUESS; i += 256) m = fmaxf(m, logits[i]);
#pragma unroll
    for (int off = 32; off > 0; off >>= 1) m = fmaxf(m, __shfl_xor(m, off, 64));
    if (lane == 0) sm[wv] = m;
    __syncthreads();
    m = fmaxf(fmaxf(sm[0], sm[1]), fmaxf(sm[2], sm[3]));
    float s = 0.0f;
    for (int i = tid; i < NGUESS; i += 256) s += expf(logits[i] - m);
#pragma unroll
    for (int off = 32; off > 0; off >>= 1) s += __shfl_xor(s, off, 64);
    if (lane == 0) sm[4 + wv] = s;
    __syncthreads();
    s = sm[4] + sm[5] + sm[6] + sm[7];
    float inv = 1.0f / s;
    for (int i = tid; i < NGUESS; i += 256) out[i] = expf(logits[i] - m) * inv;
}

// ---------------------------------------------------------------------------
extern "C" void kernel_launch(void* const* d_in, const int* in_sizes, int n_in,
                              void* d_out, int out_size, void* d_ws, size_t ws_size,
                              hipStream_t stream) {
    const int*   guesses   = (const int*)d_in[0];
    const int*   feedbacks = (const int*)d_in[1];
    const float* gemb      = (const float*)d_in[2];
    const float* femb      = (const float*)d_in[3];
    const float* Wih       = (const float*)d_in[4];
    const float* Whh       = (const float*)d_in[5];
    const float* bih       = (const float*)d_in[6];
    const float* bhh       = (const float*)d_in[7];
    const float* Wfc       = (const float*)d_in[8];
    const float* bfc       = (const float*)d_in[9];

    float* ws       = (float*)d_ws;
    float* xs       = ws;                              // 512*2048 f   (4 MB)
    float* GX       = xs + (size_t)T_STEPS * H_DIM;    // 512*8192 f   (16 MB)
    u64*   hseq     = (u64*)(GX + (size_t)T_STEPS * G_DIM);  // 2*2048 u64
    unsigned* flags = (unsigned*)(hseq + 2 * H_DIM);   // 256 u32
    float* hfinal   = (float*)(flags + NWG);           // 2048 f
    float* logits   = hfinal + H_DIM;                  // 4096 f
    float* out      = (float*)d_out;

    // reset seq tags + flags every call (graph replays include this)
    hipMemsetAsync(hseq, 0, 2 * H_DIM * sizeof(u64) + NWG * sizeof(unsigned),
                   stream);

    embed_kernel<<<T_STEPS, 256, 0, stream>>>(guesses, feedbacks, gemb, femb, xs);

    dim3 g2(G_DIM / 64, T_STEPS / 64);                 // 128 x 8
    gx_gemm<<<g2, 256, 0, stream>>>(xs, Wih, bih, bhh, GX);

    {
        // cooperative launch solely for the co-residency guarantee
        void* args[] = { (void*)&Whh, (void*)&GX, (void*)&xs,
                         (void*)&hseq, (void*)&flags, (void*)&hfinal };
        hipLaunchCooperativeKernel((const void*)lstm_loop, dim3(NWG), dim3(1024),
                                   args, 0, stream);
    }

    fc_kernel<<<NGUESS / 16, 256, 0, stream>>>(Wfc, bfc, hfinal, logits);
    softmax_kernel<<<1, 256, 0, stream>>>(logits, out);
}

// Round 7
// 2407.080 us; speedup vs baseline: 1.0220x; 1.0220x over previous
//
#include <hip/hip_runtime.h>

#define T_STEPS 512
#define H_DIM   2048
#define G_DIM   8192   // 4*H
#define NGUESS  4096
#define NWG     256
#define NTHR    512    // 8 waves

typedef unsigned long long u64;

// exp2-based fast activations (v_exp_f32 + v_rcp_f32), saturation-safe.
#define LOG2E 1.4426950408889634f
__device__ __forceinline__ float fast_sig(float x) {
    return __builtin_amdgcn_rcpf(1.0f + __builtin_amdgcn_exp2f(-LOG2E * x));
}
__device__ __forceinline__ float fast_tanh(float x) {
    float t = __builtin_amdgcn_exp2f(2.0f * LOG2E * x);
    return 1.0f - 2.0f * __builtin_amdgcn_rcpf(t + 1.0f);
}

#define ALOAD(p)    __hip_atomic_load((p), __ATOMIC_RELAXED, __HIP_MEMORY_SCOPE_AGENT)
#define ASTORE(p,v) __hip_atomic_store((p), (v), __ATOMIC_RELAXED, __HIP_MEMORY_SCOPE_AGENT)

// ---------------------------------------------------------------------------
// Kernel 1: gather embeddings -> xs[T][2048]
// ---------------------------------------------------------------------------
__global__ void embed_kernel(const int* __restrict__ guesses,
                             const int* __restrict__ feedbacks,
                             const float* __restrict__ gemb,
                             const float* __restrict__ femb,
                             float* __restrict__ xs) {
    int t = blockIdx.x;                      // 512 blocks
    int g = guesses[t];
    int f = feedbacks[t];
    const float4* gs = (const float4*)(gemb + (size_t)g * 1024);
    const float4* fs = (const float4*)(femb + (size_t)f * 1024);
    float4* xg = (float4*)(xs + (size_t)t * H_DIM);
    int tid = threadIdx.x;                   // 256 threads
    xg[tid]       = gs[tid];
    xg[256 + tid] = fs[tid];
}

// ---------------------------------------------------------------------------
// Kernel 2: GX[t][r] = dot(W_ih[r], xs[t]) + b_ih[r] + b_hh[r]
// ---------------------------------------------------------------------------
__global__ void gx_gemm(const float* __restrict__ xs,
                        const float* __restrict__ Wih,
                        const float* __restrict__ bih,
                        const float* __restrict__ bhh,
                        float* __restrict__ GX) {
    __shared__ float As[64][17];
    __shared__ float Bs[64][17];
    int r0 = blockIdx.x * 64;
    int t0 = blockIdx.y * 64;
    int tid = threadIdx.x;
    int tx = tid & 15;
    int ty = tid >> 4;
    int lr = tid >> 2;
    int lk = (tid & 3) * 4;
    float acc[4][4] = {};

    for (int k0 = 0; k0 < H_DIM; k0 += 16) {
        const float* xp = xs  + (size_t)(t0 + lr) * H_DIM + k0 + lk;
        const float* wp = Wih + (size_t)(r0 + lr) * H_DIM + k0 + lk;
        As[lr][lk + 0] = xp[0]; As[lr][lk + 1] = xp[1];
        As[lr][lk + 2] = xp[2]; As[lr][lk + 3] = xp[3];
        Bs[lr][lk + 0] = wp[0]; Bs[lr][lk + 1] = wp[1];
        Bs[lr][lk + 2] = wp[2]; Bs[lr][lk + 3] = wp[3];
        __syncthreads();
#pragma unroll
        for (int kk = 0; kk < 16; ++kk) {
            float a[4], b[4];
#pragma unroll
            for (int i = 0; i < 4; ++i) a[i] = As[ty * 4 + i][kk];
#pragma unroll
            for (int j = 0; j < 4; ++j) b[j] = Bs[tx * 4 + j][kk];
#pragma unroll
            for (int i = 0; i < 4; ++i)
#pragma unroll
                for (int j = 0; j < 4; ++j) acc[i][j] += a[i] * b[j];
        }
        __syncthreads();
    }
#pragma unroll
    for (int i = 0; i < 4; ++i)
#pragma unroll
        for (int j = 0; j < 4; ++j) {
            int t = t0 + ty * 4 + i;
            int r = r0 + tx * 4 + j;
            GX[(size_t)t * G_DIM + r] = acc[i][j] + bih[r] + bhh[r];
        }
}

// ---------------------------------------------------------------------------
// Kernel 3: sequential LSTM, W_hh register-resident, direct tagged-data poll
// (R3 semantics), restructured dot for LDS bandwidth:
//   - 512 threads = 8 waves; wave v owns 4 gate rows 4v..4v+3.
//   - h in LDS as float4; dot reads ds_read_b128 (8 per wave per step).
//   - weights float4 wreg[4][8]: lane l, row rr, j -> W[row][j*256+4l .. +3].
//   - staging: each thread polls 4 contiguous tagged u64s, writes one b128.
// Data words: (step<<32)|float_bits, double-buffered by step parity; memset
// each call -> no ABA across graph replays. 2-slot overwrite safety: a WG
// publishes step t+1 only after consuming all of step t.
// ---------------------------------------------------------------------------
__global__ void __launch_bounds__(NTHR, 2)
lstm_loop(const float* __restrict__ Whh,
          const float* __restrict__ GX,
          const float* __restrict__ xs,
          u64* __restrict__ hseq,       // [2][H_DIM] packed (seq, value)
          float* __restrict__ hfinal) { // [H_DIM] final h
    __shared__ float4 h_lds4[H_DIM / 4];   // h as float4
    __shared__ float gates[32];

    const int wg   = blockIdx.x;        // 256
    const int base = wg * 8;            // unit base
    const int tid  = threadIdx.x;       // 0..511
    const int lane = tid & 63;
    const int wv   = tid >> 6;          // wave 0..7

    // rows owned: r_loc = 4*wv + rr, rr = 0..3 (gate = r_loc>>3, unit = r_loc&7)
    int grow[4];
#pragma unroll
    for (int rr = 0; rr < 4; ++rr) {
        int r_loc = 4 * wv + rr;
        grow[rr] = (r_loc >> 3) * H_DIM + base + (r_loc & 7);
    }

    // ---- preload W_hh rows as float4 (lane l: k = j*256 + 4l + m) ----
    float4 wreg[4][8];
#pragma unroll
    for (int rr = 0; rr < 4; ++rr) {
        const float4* W = (const float4*)(Whh + (size_t)grow[rr] * H_DIM) + lane;
#pragma unroll
        for (int j = 0; j < 8; ++j)
            wreg[rr][j] = W[j * 64];
    }

    // ---- peeled step t=0: h==0, gates = GX[0] ----
    if (tid < 32)
        gates[tid] = GX[(tid >> 3) * H_DIM + base + (tid & 7)];
    __syncthreads();
    if (tid < 8) {
        int u = tid;
        float gi = gates[0 * 8 + u];
        float gg = gates[2 * 8 + u];
        float go = gates[3 * 8 + u];
        float c  = fast_sig(gi) * fast_tanh(gg);       // c_in = 0 at t=0
        float hn = fast_sig(go) * fast_tanh(c);
        u64 word = (1ull << 32) | (u64)__float_as_uint(hn);
        ASTORE(hseq + H_DIM + base + u, word);
    }

    for (int t = 1; t < T_STEPS; ++t) {
        const float* gx = GX + (size_t)t * G_DIM;
        // independent loads issued early (hide under the poll)
        float gxv[4];
#pragma unroll
        for (int rr = 0; rr < 4; ++rr) gxv[rr] = gx[grow[rr]];
        float c_in = 0.0f;
        if (tid < 8) c_in = xs[(size_t)t * H_DIM + base + tid];

        // ---- joint poll of 4 contiguous tagged words (overlapped trips) ----
        u64* slot = hseq + (size_t)(t & 1) * H_DIM + 4 * tid;
        const unsigned want = (unsigned)t;
        u64 a0 = ALOAD(slot + 0), a1 = ALOAD(slot + 1);
        u64 a2 = ALOAD(slot + 2), a3 = ALOAD(slot + 3);
        while (((unsigned)(a0 >> 32) != want) | ((unsigned)(a1 >> 32) != want) |
               ((unsigned)(a2 >> 32) != want) | ((unsigned)(a3 >> 32) != want)) {
            __builtin_amdgcn_s_sleep(1);
            a0 = ALOAD(slot + 0); a1 = ALOAD(slot + 1);
            a2 = ALOAD(slot + 2); a3 = ALOAD(slot + 3);
        }
        float4 hv4;
        hv4.x = __uint_as_float((unsigned)a0);
        hv4.y = __uint_as_float((unsigned)a1);
        hv4.z = __uint_as_float((unsigned)a2);
        hv4.w = __uint_as_float((unsigned)a3);
        h_lds4[tid] = hv4;                 // one ds_write_b128
        __syncthreads();   // B1

        // ---- dot: 4 rows per wave, ds_read_b128 ----
        float acc0 = 0.0f, acc1 = 0.0f, acc2 = 0.0f, acc3 = 0.0f;
#pragma unroll
        for (int j = 0; j < 8; ++j) {
            float4 h4 = h_lds4[j * 64 + lane];
            acc0 += wreg[0][j].x * h4.x + wreg[0][j].y * h4.y +
                    wreg[0][j].z * h4.z + wreg[0][j].w * h4.w;
            acc1 += wreg[1][j].x * h4.x + wreg[1][j].y * h4.y +
                    wreg[1][j].z * h4.z + wreg[1][j].w * h4.w;
            acc2 += wreg[2][j].x * h4.x + wreg[2][j].y * h4.y +
                    wreg[2][j].z * h4.z + wreg[2][j].w * h4.w;
            acc3 += wreg[3][j].x * h4.x + wreg[3][j].y * h4.y +
                    wreg[3][j].z * h4.z + wreg[3][j].w * h4.w;
        }
#pragma unroll
        for (int off = 32; off > 0; off >>= 1) {
            acc0 += __shfl_xor(acc0, off, 64);
            acc1 += __shfl_xor(acc1, off, 64);
            acc2 += __shfl_xor(acc2, off, 64);
            acc3 += __shfl_xor(acc3, off, 64);
        }
        if (lane == 0) {
            gates[4 * wv + 0] = acc0 + gxv[0];
            gates[4 * wv + 1] = acc1 + gxv[1];
            gates[4 * wv + 2] = acc2 + gxv[2];
            gates[4 * wv + 3] = acc3 + gxv[3];
        }
        __syncthreads();   // B2

        if (tid < 8) {
            int u = tid;
            float gi = gates[0 * 8 + u];
            float gf = gates[1 * 8 + u];
            float gg = gates[2 * 8 + u];
            float go = gates[3 * 8 + u];
            float c  = fast_sig(gf) * c_in + fast_sig(gi) * fast_tanh(gg);
            float hn = fast_sig(go) * fast_tanh(c);
            u64 word = ((u64)(unsigned)(t + 1) << 32) | (u64)__float_as_uint(hn);
            ASTORE(hseq + (size_t)((t + 1) & 1) * H_DIM + base + u, word);
            if (t == T_STEPS - 1)
                hfinal[base + u] = hn;   // kernel-end release publishes this
        }
        // no trailing barrier: t+1 polls self-synchronize; h_lds/gates writes
        // at t+1 are ordered by B1(t+1)/B2(t+1) against this step's readers.
    }
}

// ---------------------------------------------------------------------------
// Kernel 4: logits[r] = dot(W_fc[r], h) + b_fc[r]
// ---------------------------------------------------------------------------
__global__ void fc_kernel(const float* __restrict__ Wfc,
                          const float* __restrict__ bfc,
                          const float* __restrict__ h,
                          float* __restrict__ logits) {
    int wg = blockIdx.x;           // 256
    int tid = threadIdx.x;
    int lane = tid & 63, wv = tid >> 6;
    int r0 = wg * 16;
    const float4* hv = (const float4*)h;
    for (int rr = wv; rr < 16; rr += 4) {
        int r = r0 + rr;
        const float4* wrow = (const float4*)(Wfc + (size_t)r * H_DIM);
        float acc = 0.0f;
#pragma unroll
        for (int c = 0; c < 8; ++c) {
            float4 w4 = wrow[c * 64 + lane];
            float4 h4 = hv[c * 64 + lane];
            acc += w4.x * h4.x + w4.y * h4.y + w4.z * h4.z + w4.w * h4.w;
        }
#pragma unroll
        for (int off = 32; off > 0; off >>= 1) acc += __shfl_xor(acc, off, 64);
        if (lane == 0) logits[r] = acc + bfc[r];
    }
}

// ---------------------------------------------------------------------------
// Kernel 5: softmax over 4096 logits -> out
// ---------------------------------------------------------------------------
__global__ void softmax_kernel(const float* __restrict__ logits,
                               float* __restrict__ out) {
    __shared__ float sm[8];
    int tid = threadIdx.x, lane = tid & 63, wv = tid >> 6;
    float m = -1e30f;
    for (int i = tid; i < NGUESS; i += 256) m = fmaxf(m, logits[i]);
#pragma unroll
    for (int off = 32; off > 0; off >>= 1) m = fmaxf(m, __shfl_xor(m, off, 64));
    if (lane == 0) sm[wv] = m;
    __syncthreads();
    m = fmaxf(fmaxf(sm[0], sm[1]), fmaxf(sm[2], sm[3]));
    float s = 0.0f;
    for (int i = tid; i < NGUESS; i += 256) s += expf(logits[i] - m);
#pragma unroll
    for (int off = 32; off > 0; off >>= 1) s += __shfl_xor(s, off, 64);
    if (lane == 0) sm[4 + wv] = s;
    __syncthreads();
    s = sm[4] + sm[5] + sm[6] + sm[7];
    float inv = 1.0f / s;
    for (int i = tid; i < NGUESS; i += 256) out[i] = expf(logits[i] - m) * inv;
}

// ---------------------------------------------------------------------------
extern "C" void kernel_launch(void* const* d_in, const int* in_sizes, int n_in,
                              void* d_out, int out_size, void* d_ws, size_t ws_size,
                              hipStream_t stream) {
    const int*   guesses   = (const int*)d_in[0];
    const int*   feedbacks = (const int*)d_in[1];
    const float* gemb      = (const float*)d_in[2];
    const float* femb      = (const float*)d_in[3];
    const float* Wih       = (const float*)d_in[4];
    const float* Whh       = (const float*)d_in[5];
    const float* bih       = (const float*)d_in[6];
    const float* bhh       = (const float*)d_in[7];
    const float* Wfc       = (const float*)d_in[8];
    const float* bfc       = (const float*)d_in[9];

    float* ws     = (float*)d_ws;
    float* xs     = ws;                              // 512*2048 f   (4 MB)
    float* GX     = xs + (size_t)T_STEPS * H_DIM;    // 512*8192 f   (16 MB)
    u64*   hseq   = (u64*)(GX + (size_t)T_STEPS * G_DIM);  // 2*2048 u64
    float* hfinal = (float*)(hseq + 2 * H_DIM);      // 2048 f
    float* logits = hfinal + H_DIM;                  // 4096 f
    float* out    = (float*)d_out;

    // reset seq tags every call (graph replays include this) -> no ABA
    hipMemsetAsync(hseq, 0, 2 * H_DIM * sizeof(u64), stream);

    embed_kernel<<<T_STEPS, 256, 0, stream>>>(guesses, feedbacks, gemb, femb, xs);

    dim3 g2(G_DIM / 64, T_STEPS / 64);               // 128 x 8
    gx_gemm<<<g2, 256, 0, stream>>>(xs, Wih, bih, bhh, GX);

    {
        // cooperative launch solely for the co-residency guarantee
        void* args[] = { (void*)&Whh, (void*)&GX, (void*)&xs,
                         (void*)&hseq, (void*)&hfinal };
        hipLaunchCooperativeKernel((const void*)lstm_loop, dim3(NWG), dim3(NTHR),
                                   args, 0, stream);
    }

    fc_kernel<<<NGUESS / 16, 256, 0, stream>>>(Wfc, bfc, hfinal, logits);
    softmax_kernel<<<1, 256, 0, stream>>>(logits, out);
}